// Round 1
// baseline (215.607 us; speedup 1.0000x reference)
//
#include <hip/hip_runtime.h>

// CRF score reduction: B=512, S=2048, T=32.
// total = sum_b rowsum(trans[tags[b,0]])
//       + sum emissions[b,0,:]
//       + sum_{t>=1} emissions[b,t,:]*mask[b,t]
//       + 32 * sum_{t>=1} trans[tags[b,t-1],tags[b,t]]*mask[b,t]
// Memory-bound streaming reduction over ~137 MiB -> roofline ~22 us.

constexpr int BB = 512;
constexpr int SS = 2048;
constexpr int TT = 32;

__global__ __launch_bounds__(256) void crf_sum_kernel(
    const float* __restrict__ emissions,
    const int*   __restrict__ tags,
    const float* __restrict__ mask,
    const float* __restrict__ transitions,
    float*       __restrict__ out)
{
    __shared__ float s_trans[TT * TT];
    __shared__ float s_rowsum[TT];
    __shared__ float s_red[4];

    const int tid = threadIdx.x;

    // Stage 32x32 transitions in LDS (4 KiB), then per-tag rowsums.
    for (int i = tid; i < TT * TT; i += blockDim.x)
        s_trans[i] = transitions[i];
    __syncthreads();
    if (tid < TT) {
        float r = 0.f;
        #pragma unroll
        for (int k = 0; k < TT; ++k) r += s_trans[tid * TT + k];
        s_rowsum[tid] = r;
    }
    __syncthreads();

    float sum = 0.f;
    const int gsize = gridDim.x * blockDim.x;
    const int gtid  = blockIdx.x * blockDim.x + tid;

    // ---- emissions stream: float4 loads, weight (t==0 ? 1 : mask[b,t]) ----
    const float4* em4 = (const float4*)emissions;
    const int n4 = BB * SS * TT / 4;          // 8,388,608 float4s
    for (int i = gtid; i < n4; i += gsize) {
        float4 v = em4[i];
        int row = i >> 3;                     // (i*4)/32 -> (b*S + t)
        int t   = row & (SS - 1);
        float w = (t == 0) ? 1.0f : mask[row]; // 8 lanes share one mask elem
        sum += w * ((v.x + v.y) + (v.z + v.w));
    }

    // ---- tag-step stream: int4 tags + float4 mask, LDS gather ----
    const int4*   tg4 = (const int4*)tags;
    const float4* mk4 = (const float4*)mask;
    const int nu = BB * SS / 4;               // 262,144
    for (int u = gtid; u < nu; u += gsize) {
        int4   tg = tg4[u];
        float4 mk = mk4[u];
        int j0 = u * 4;
        int t0 = j0 & (SS - 1);
        if (t0 == 0) {
            sum += s_rowsum[tg.x];            // score0 transition rowsum
        } else {
            int prev = tags[j0 - 1];
            sum += 32.0f * s_trans[prev * TT + tg.x] * mk.x;
        }
        sum += 32.0f * s_trans[tg.x * TT + tg.y] * mk.y;
        sum += 32.0f * s_trans[tg.y * TT + tg.z] * mk.z;
        sum += 32.0f * s_trans[tg.z * TT + tg.w] * mk.w;
    }

    // ---- wave (64) shuffle reduce, then cross-wave via LDS ----
    #pragma unroll
    for (int off = 32; off > 0; off >>= 1)
        sum += __shfl_down(sum, off, 64);
    const int lane = tid & 63;
    const int wave = tid >> 6;
    if (lane == 0) s_red[wave] = sum;
    __syncthreads();
    if (tid == 0) {
        float s = (s_red[0] + s_red[1]) + (s_red[2] + s_red[3]);
        atomicAdd(out, s);
    }
}

extern "C" void kernel_launch(void* const* d_in, const int* in_sizes, int n_in,
                              void* d_out, int out_size, void* d_ws, size_t ws_size,
                              hipStream_t stream) {
    const float* emissions   = (const float*)d_in[0];
    const int*   tags        = (const int*)  d_in[1];
    const float* mask        = (const float*)d_in[2];
    const float* transitions = (const float*)d_in[3];
    float* out = (float*)d_out;

    // d_out is re-poisoned (0xAA) before every timed replay -> must zero it.
    hipMemsetAsync(out, 0, out_size * sizeof(float), stream);

    // 2048 blocks x 256 threads: 8 blocks/CU worth of waves, each thread
    // handles ~16 float4 emission loads + ~2 tag int4 groups.
    crf_sum_kernel<<<2048, 256, 0, stream>>>(emissions, tags, mask, transitions, out);
}

// Round 2
// 207.071 us; speedup vs baseline: 1.0412x; 1.0412x over previous
//
#include <hip/hip_runtime.h>

// CRF score reduction: B=512, S=2048, T=32.
// total = sum_b rowsum(trans[tags[b,0]])
//       + sum_b sum_T em[b,0,:]
//       + sum_{t>=1} em[b,t,:]*mask[b,t]
//       + 32 * sum_{t>=1} trans[tags[b,t-1],tags[b,t]]*mask[b,t]
//
// Rewritten branchless: emissions always weighted by mask[b,t]; the t==0
// row's correction (1-mask[b,0])*rowsum(em[b,0,:]) is added in the sparse
// t0==0 branch of the tag loop (512 threads total).
//
// Mandatory HBM traffic: 128 MiB em + 4 MiB tags + 4 MiB mask = 137 MiB
// -> ~20 us at the ~6.9 TB/s demonstrated by the harness's own fills.

constexpr int BB = 512;
constexpr int SS = 2048;
constexpr int TT = 32;

typedef float f4v __attribute__((ext_vector_type(4)));

__global__ __launch_bounds__(256) void crf_sum_kernel(
    const float* __restrict__ emissions,
    const int*   __restrict__ tags,
    const float* __restrict__ mask,
    const float* __restrict__ transitions,
    float*       __restrict__ out)
{
    __shared__ float s_trans[TT * TT];
    __shared__ float s_rowsum[TT];
    __shared__ float s_red[4];

    const int tid = threadIdx.x;

    // Stage 32x32 transitions in LDS (4 KiB), then per-tag rowsums.
    for (int i = tid; i < TT * TT; i += blockDim.x)
        s_trans[i] = transitions[i];
    __syncthreads();
    if (tid < TT) {
        float r = 0.f;
        #pragma unroll
        for (int k = 0; k < TT; ++k) r += s_trans[tid * TT + k];
        s_rowsum[tid] = r;
    }
    __syncthreads();

    float sum = 0.f;
    const int gsize = gridDim.x * blockDim.x;
    const int gtid  = blockIdx.x * blockDim.x + tid;

    // ---- emissions stream: nontemporal float4 loads, weight mask[b,t] ----
    // (branchless; t==0 correction handled below)
    const f4v* em4 = (const f4v*)emissions;
    const int n4 = BB * SS * TT / 4;          // 8,388,608 float4s, 16 iters/thread
    #pragma unroll 4
    for (int i = gtid; i < n4; i += gsize) {
        f4v v = __builtin_nontemporal_load(em4 + i);
        int row = i >> 3;                     // (i*4)/32 -> (b*S + t)
        sum += mask[row] * ((v.x + v.y) + (v.z + v.w));
    }

    // ---- tag-step stream: int4 tags + float4 mask, LDS gather ----
    const int4*   tg4 = (const int4*)tags;
    const float4* mk4 = (const float4*)mask;
    const int nu = BB * SS / 4;               // 262,144
    for (int u = gtid; u < nu; u += gsize) {
        int4   tg = tg4[u];
        float4 mk = mk4[u];
        int j0 = u * 4;
        int t0 = j0 & (SS - 1);
        if (t0 == 0) {
            // score0 transition rowsum + emissions t==0 mask correction
            sum += s_rowsum[tg.x];
            const f4v* erow = (const f4v*)(emissions + (size_t)(j0 >> 11 << 11) * TT);
            // j0 = b*SS here, so row index b*SS; em row base = j0*TT
            float r = 0.f;
            #pragma unroll
            for (int k = 0; k < TT / 4; ++k) {
                f4v e = ((const f4v*)(emissions + (size_t)j0 * TT))[k];
                r += (e.x + e.y) + (e.z + e.w);
            }
            sum += (1.0f - mk.x) * r;
            (void)erow;
        } else {
            int prev = tags[j0 - 1];
            sum += 32.0f * s_trans[prev * TT + tg.x] * mk.x;
        }
        sum += 32.0f * s_trans[tg.x * TT + tg.y] * mk.y;
        sum += 32.0f * s_trans[tg.y * TT + tg.z] * mk.z;
        sum += 32.0f * s_trans[tg.z * TT + tg.w] * mk.w;
    }

    // ---- wave (64) shuffle reduce, then cross-wave via LDS ----
    #pragma unroll
    for (int off = 32; off > 0; off >>= 1)
        sum += __shfl_down(sum, off, 64);
    const int lane = tid & 63;
    const int wave = tid >> 6;
    if (lane == 0) s_red[wave] = sum;
    __syncthreads();
    if (tid == 0) {
        float s = (s_red[0] + s_red[1]) + (s_red[2] + s_red[3]);
        atomicAdd(out, s);
    }
}

extern "C" void kernel_launch(void* const* d_in, const int* in_sizes, int n_in,
                              void* d_out, int out_size, void* d_ws, size_t ws_size,
                              hipStream_t stream) {
    const float* emissions   = (const float*)d_in[0];
    const int*   tags        = (const int*)  d_in[1];
    const float* mask        = (const float*)d_in[2];
    const float* transitions = (const float*)d_in[3];
    float* out = (float*)d_out;

    // d_out is re-poisoned (0xAA) before every timed replay -> must zero it.
    hipMemsetAsync(out, 0, out_size * sizeof(float), stream);

    // 2048 blocks x 256 threads = 8 blocks/CU, 16 float4 emission loads/thread.
    crf_sum_kernel<<<2048, 256, 0, stream>>>(emissions, tags, mask, transitions, out);
}

// Round 3
// 206.598 us; speedup vs baseline: 1.0436x; 1.0023x over previous
//
#include <hip/hip_runtime.h>

// CRF score reduction: B=512, S=2048, T=32.
// total = sum_b rowsum(trans[tags[b,0]])
//       + sum_b sum_T em[b,0,:]
//       + sum_{t>=1} em[b,t,:]*mask[b,t]
//       + 32 * sum_{t>=1} trans[tags[b,t-1],tags[b,t]]*mask[b,t]
//
// Branchless emissions stream (always *mask), t==0 correction folded into
// the sparse t0==0 branch of the tag loop. Grid geometry chosen so the
// emissions loop is EXACTLY 16 iterations/thread -> fully unrolled, all 16
// nontemporal dwordx4 loads in flight before the adds (max MLP).
//
// Mandatory HBM traffic: 128 MiB em + 4 MiB tags + 4 MiB mask = 137 MiB
// -> ~21 us at the ~6.9 TB/s the harness's own fills demonstrate.

constexpr int BB = 512;
constexpr int SS = 2048;
constexpr int TT = 32;

constexpr int BLOCKS  = 2048;
constexpr int THREADS = 256;
constexpr int GSIZE   = BLOCKS * THREADS;           // 524,288
constexpr int N4      = BB * SS * TT / 4;           // 8,388,608
constexpr int EM_ITERS = N4 / GSIZE;                // exactly 16
static_assert(N4 % GSIZE == 0, "exact tiling");

typedef float f4v __attribute__((ext_vector_type(4)));

__global__ __launch_bounds__(THREADS) void crf_sum_kernel(
    const float* __restrict__ emissions,
    const int*   __restrict__ tags,
    const float* __restrict__ mask,
    const float* __restrict__ transitions,
    float*       __restrict__ out)
{
    __shared__ float s_trans[TT * TT];
    __shared__ float s_rowsum[TT];
    __shared__ float s_red[4];

    const int tid  = threadIdx.x;
    const int gtid = blockIdx.x * THREADS + tid;

    // Stage 32x32 transitions in LDS (4 KiB), then per-tag rowsums.
    for (int i = tid; i < TT * TT; i += THREADS)
        s_trans[i] = transitions[i];
    __syncthreads();
    if (tid < TT) {
        float r = 0.f;
        #pragma unroll
        for (int k = 0; k < TT; ++k) r += s_trans[tid * TT + k];
        s_rowsum[tid] = r;
    }
    __syncthreads();

    // ---- emissions stream: 16 nontemporal float4 loads, fully unrolled ----
    const f4v* em4 = (const f4v*)emissions;
    f4v   v[EM_ITERS];
    float w[EM_ITERS];
    #pragma unroll
    for (int k = 0; k < EM_ITERS; ++k) {
        int i = gtid + k * GSIZE;
        v[k] = __builtin_nontemporal_load(em4 + i);
        w[k] = mask[i >> 3];                  // (i*4)/32 -> (b*S + t)
    }
    float sum = 0.f;
    #pragma unroll
    for (int k = 0; k < EM_ITERS; ++k)
        sum += w[k] * ((v[k].x + v[k].y) + (v[k].z + v[k].w));

    // ---- tag-step stream: int4 tags + float4 mask, LDS gather ----
    // nu = 262,144 < GSIZE: each thread does 0 or 1 iterations.
    constexpr int NU = BB * SS / 4;
    if (gtid < NU) {
        const int u = gtid;
        int4   tg = ((const int4*)tags)[u];
        float4 mk = ((const float4*)mask)[u];
        int j0 = u * 4;
        int t0 = j0 & (SS - 1);
        if (t0 == 0) {
            // score0 transition rowsum + emissions t==0 mask correction
            sum += s_rowsum[tg.x];
            float r = 0.f;
            #pragma unroll
            for (int k = 0; k < TT / 4; ++k) {
                f4v e = ((const f4v*)(emissions + (size_t)j0 * TT))[k];
                r += (e.x + e.y) + (e.z + e.w);
            }
            sum += (1.0f - mk.x) * r;
        } else {
            int prev = tags[j0 - 1];
            sum += 32.0f * s_trans[prev * TT + tg.x] * mk.x;
        }
        sum += 32.0f * s_trans[tg.x * TT + tg.y] * mk.y;
        sum += 32.0f * s_trans[tg.y * TT + tg.z] * mk.z;
        sum += 32.0f * s_trans[tg.z * TT + tg.w] * mk.w;
    }

    // ---- wave (64) shuffle reduce, then cross-wave via LDS ----
    #pragma unroll
    for (int off = 32; off > 0; off >>= 1)
        sum += __shfl_down(sum, off, 64);
    const int lane = tid & 63;
    const int wave = tid >> 6;
    if (lane == 0) s_red[wave] = sum;
    __syncthreads();
    if (tid == 0) {
        float s = (s_red[0] + s_red[1]) + (s_red[2] + s_red[3]);
        atomicAdd(out, s);
    }
}

extern "C" void kernel_launch(void* const* d_in, const int* in_sizes, int n_in,
                              void* d_out, int out_size, void* d_ws, size_t ws_size,
                              hipStream_t stream) {
    const float* emissions   = (const float*)d_in[0];
    const int*   tags        = (const int*)  d_in[1];
    const float* mask        = (const float*)d_in[2];
    const float* transitions = (const float*)d_in[3];
    float* out = (float*)d_out;

    // d_out is re-poisoned (0xAA) before every timed replay -> must zero it.
    hipMemsetAsync(out, 0, out_size * sizeof(float), stream);

    crf_sum_kernel<<<BLOCKS, THREADS, 0, stream>>>(emissions, tags, mask, transitions, out);
}